// Round 19
// baseline (76.775 us; speedup 1.0000x reference)
//
#include <hip/hip_runtime.h>
#include <math.h>

// CrowdDet RetinaNet loss constants
#define POS_T 0.5f
#define NEG_T 0.4f
#define F_ALPHA 0.25f
#define SL1_BETA 0.1f

// Pruning geometry (validated R10-R18): 8x8 cells of 128px, 6 area classes.
#define NCELL 8
#define NCLASS 6
#define NB (NCELL * NCELL * NCLASS)   // 384 buckets
#define KEEP_T 0.37f
#define APT 4                          // anchors per thread in k1/k3

// Anchor legacy-area class thresholds: 289 * 2.5^k (exact in f32).
__device__ __constant__ float AT[7] = {
    289.f, 722.5f, 1806.25f, 4515.625f, 11289.0625f, 28222.65625f, 70556.640625f};

__device__ __forceinline__ float smooth_l1(float d) {
    d = fabsf(d);
    return d < SL1_BETA ? 0.5f * d * d / SL1_BETA : d - SL1_BETA;
}

__device__ __forceinline__ int bucket_of(const float4 av) {
    const float aw = av.z - av.x + 1.f, ah = av.w - av.y + 1.f;
    const float Aa = aw * ah;
    const float cx = 0.5f * (av.x + av.z);
    const float cy = 0.5f * (av.y + av.w);
    const int cxi = min(NCELL - 1, max(0, (int)(cx * (1.0f / 128.f))));
    const int cyi = min(NCELL - 1, max(0, (int)(cy * (1.0f / 128.f))));
    const int k = (Aa > AT[1]) + (Aa > AT[2]) + (Aa > AT[3])
                + (Aa > AT[4]) + (Aa > AT[5]);
    return (k << 6) | (cyi << 3) | cxi;
}

// ---- K1: ws zero + anchor buckets/hist (blocks < nblk) + candidate lists
//          for bucket bk = blockIdx.x (all NB blocks). Lists depend only on
//          gt/im_info, so building them here removes their serialization
//          behind the histogram. Bodies verbatim R18 (absmax 0.0). ----------
__global__ __launch_bounds__(256) void k1_assign_lists(
    const float* __restrict__ anchors, const float* __restrict__ gt,
    const float* __restrict__ im_info,
    int* __restrict__ bucketid, int* __restrict__ blockhist, // [nblk][NB]
    int* __restrict__ cnt_arr,
    float4* __restrict__ qLo, float* __restrict__ qA,
    float4* __restrict__ eLo, float* __restrict__ eCls,
    double* __restrict__ ws, int A, int G, int Gp, int B, int nblk)
{
#pragma clang fp contract(off)
    __shared__ int lh[NB];
    const int t = threadIdx.x;
    const int blk = blockIdx.x;
    const int gid = blk * 256 + t;
    if (gid < 50) ws[gid] = 0.0;                 // accumulators + done ctr

    // --- Part 1: hist + buckets (blocks < nblk) ---
    if (blk < nblk) {
        for (int i = t; i < NB; i += 256) lh[i] = 0;
        __syncthreads();
        #pragma unroll
        for (int u = 0; u < APT; ++u) {
            const int ai = blk * (256 * APT) + u * 256 + t;  // unit-stride
            if (ai < A) {
                const float4 av = *reinterpret_cast<const float4*>(anchors + 4 * (size_t)ai);
                const int bk = bucket_of(av);
                bucketid[ai] = bk;
                atomicAdd(&lh[bk], 1);           // LDS atomic, cheap
            }
        }
        __syncthreads();
        for (int j = t; j < NB; j += 256)
            blockhist[(size_t)blk * NB + j] = lh[j];   // coalesced burst
    }

    // --- Part 2: candidate lists for bucket bk = blk (validated keep-test;
    //     compaction preserves ascending gt order -> first-max intact) ---
    const int bk = blk;
    const int wid = t >> 6, lane = t & 63;
    const int cxi = bk & 7, cyi = (bk >> 3) & 7, k = bk >> 6;
    const float cx0 = cxi * 128.f, cx1 = cx0 + 128.f;
    const float cy0 = cyi * 128.f, cy1 = cy0 + 128.f;
    const float Alo = AT[k], Ahi = AT[k + 1];

    for (int b = wid; b < B; b += 4) {
        const int nv = __builtin_amdgcn_readfirstlane((int)im_info[b * 6 + 5]);
        const int li = b * NB + bk;
        const size_t lb = (size_t)li * Gp;

        int cnt = 0;
        for (int base = 0; base < nv; base += 64) {
            const int j = base + lane;
            bool keep = false;
            float g0 = 0.f, g1 = 0.f, g2 = 0.f, g3 = 0.f, cls = 0.f;
            float area = 0.f, g2p = 0.f, g3p = 0.f;
            if (j < nv) {
                const float* sp = gt + ((size_t)b * G + j) * 5;
                g0 = sp[0]; g1 = sp[1]; g2 = sp[2]; g3 = sp[3]; cls = sp[4];
                area = (g2 - g0 + 1.f) * (g3 - g1 + 1.f);   // exact ref order
                g2p = g2 + 1.f; g3p = g3 + 1.f;             // pre-added +1
                const float wg = g2p - g0;
                const float hg = g3p - g1;
                const float ox = fminf(cx1 + 129.f, g2p) - fmaxf(cx0 - 128.f, g0);
                const float oy = fminf(cy1 + 129.f, g3p) - fmaxf(cy0 - 128.f, g1);
                keep = (ox >= KEEP_T * wg) && (oy >= KEEP_T * hg)
                    && (area >= KEEP_T * Alo) && (KEEP_T * area <= Ahi);
            }
            const unsigned long long m = __ballot(keep);
            if (keep) {
                const int pos = cnt + __popcll(m & ((1ull << lane) - 1ull));
                qLo[lb + pos] = make_float4(g0, g1, g2p, g3p);
                qA[lb + pos] = area;
                eLo[lb + pos] = make_float4(g0, g1, g2, g3);
                eCls[lb + pos] = cls;
            }
            cnt += __popcll(m);
        }
        if (lane == 0) cnt_arr[li] = cnt;
    }
}

// ---- K2: scan-only — exclusive prefix of bh[blk][bk] over blk + totals ----
__global__ __launch_bounds__(256) void k2_scan(
    int* __restrict__ bh, int* __restrict__ totals, int nblk)
{
    const int bk = blockIdx.x, t = threadIdx.x;
    __shared__ int s[256];
    const int v = (t < nblk) ? bh[(size_t)t * NB + bk] : 0;
    s[t] = v;
    __syncthreads();
    for (int d = 1; d < 256; d <<= 1) {
        const int u = (t >= d) ? s[t - d] : 0;
        __syncthreads();
        s[t] += u;
        __syncthreads();
    }
    if (t < nblk) bh[(size_t)t * NB + bk] = s[t] - v;   // exclusive prefix
    if (t == 255) totals[bk] = s[255];
}

// ---- K3: bases + place anchors + PRE-GATHER per-anchor data to slot order --
// Verbatim R18 (absmax 0.0).
__global__ __launch_bounds__(256) void k3_place(
    const float* __restrict__ anchors, const float* __restrict__ pred_cls,
    const int* __restrict__ bucketid, const int* __restrict__ bh,
    const int* __restrict__ totals,
    int* __restrict__ sortedA, int* __restrict__ sortedbkt,
    float4* __restrict__ sortedAnc, float4* __restrict__ sortedMeta,
    float2* __restrict__ sortedPc, int A, int B)
{
#pragma clang fp contract(off)
    __shared__ int lh[NB];
    __shared__ int sbase[NB];
    const int t = threadIdx.x, blk = blockIdx.x;
    for (int i = t; i < NB; i += 256) lh[i] = 0;
    if (t < 64) {
        int carry = 0;
        #pragma unroll
        for (int r = 0; r < NB / 64; ++r) {
            int v = totals[r * 64 + t];            // exact (unpadded) bases
            const int orig = v;
            for (int d = 1; d < 64; d <<= 1) {
                const int u = __shfl_up(v, d);
                if (t >= d) v += u;
            }
            sbase[r * 64 + t] = carry + v - orig;  // exclusive
            carry += __shfl(v, 63);
        }
    }
    __syncthreads();

    #pragma unroll
    for (int u = 0; u < APT; ++u) {
        const int ai = blk * (256 * APT) + u * 256 + t;   // unit-stride reads
        if (ai < A) {
            const int bk = bucketid[ai];
            const int lrk = atomicAdd(&lh[bk], 1);
            const int slot = sbase[bk] + bh[(size_t)blk * NB + bk] + lrk;
            const float4 av = *reinterpret_cast<const float4*>(anchors + 4 * (size_t)ai);
            const float aw = av.z - av.x + 1.f;            // exact ref ops
            const float ah = av.w - av.y + 1.f;
            sortedA[slot] = ai;
            sortedbkt[slot] = bk;
            sortedAnc[slot] = make_float4(av.x, av.y, av.z + 1.f, av.w + 1.f);
            sortedMeta[slot] = make_float4(aw * ah, aw, ah, 0.f);
            const float pc0 = pred_cls[ai];
            const float pc1 = (B > 1) ? pred_cls[(size_t)A + ai] : 0.f;
            sortedPc[slot] = make_float2(pc0, pc1);
        }
    }
}

// ---- K4: main loss (verbatim R18) + fused last-block finalize (verbatim
//          R14/R15, absmax 0.0 at this block scale). -------------------------
__global__ __launch_bounds__(256) void retina_loss_kernel(
    const float* __restrict__ pred_reg,
    const int* __restrict__ sortedA, const int* __restrict__ sortedbkt,
    const float4* __restrict__ sortedAnc, const float4* __restrict__ sortedMeta,
    const float2* __restrict__ sortedPc, const float* __restrict__ pred_cls,
    const int* __restrict__ cnt_arr,
    const float4* __restrict__ qLo, const float* __restrict__ qA,
    const float4* __restrict__ eLo, const float* __restrict__ eCls,
    int A, int Gp, int B,
    double* __restrict__ ws, float* __restrict__ out)
{
#pragma clang fp contract(off)
    const int t = threadIdx.x;
    const int i_raw = blockIdx.x * 256 + t;
    const bool live = i_raw < A;
    const int i = min(i_raw, A - 1);

    const int a = sortedA[i];                 // coalesced
    const int bk = sortedbkt[i];              // near-uniform per wave
    const float4 anc = sortedAnc[i];          // {a0, a1, a2p, a3p}
    const float4 meta = sortedMeta[i];        // {area_a, aw, ah, -}
    const float2 pc = sortedPc[i];
    const float a0 = anc.x, a1 = anc.y, a2p = anc.z, a3p = anc.w;
    const float area_a = meta.x, aw = meta.y, ah = meta.z;

    float lc = 0.f, lr = 0.f;
    int fg = 0;

    for (int b = 0; b < B; ++b) {
        const int li = b * NB + bk;
        const int cnt = cnt_arr[li];
        const size_t lb = (size_t)li * Gp;

        // Division-free IoU argmax (validated): iou monotone in inter/S =>
        // strict cross-mul > == first-max (jnp.argmax tie-break). Induction-
        // only addresses -> loads pipeline ahead.
        float bi = -1.f, bS = 1.f;
        int argp = 0;
        for (int g = 0; g < cnt; ++g) {
            const float4 q = qLo[lb + g];     // broadcast (uniform-ish bk)
            const float sg = qA[lb + g];
            const float iw = fminf(a2p, q.z) - fmaxf(a0, q.x);
            const float ih = fminf(a3p, q.w) - fmaxf(a1, q.y);
            const float inter = fmaxf(iw, 0.f) * fmaxf(ih, 0.f);
            const float S = area_a + sg;
            const bool upd = inter * bS > bi * S;
            bi   = upd ? inter : bi;
            bS   = upd ? S     : bS;
            argp = upd ? g     : argp;
        }

        if (live) {
            // ONE division, exact ref expr: inter/((area_a+area_g)-inter).
            // cnt==0 -> max_ov=-0.5 -> bg (validated: pruned ious < 0.37).
            const float max_ov = bi / (bS - bi);

            float label = 0.f;
            bool valid = true;
            if (max_ov >= POS_T) {
                label = eCls[lb + argp];
            } else if (max_ov >= NEG_T) {
                valid = false;                 // ignore band
            }
            const int f = (label > 0.f) ? 1 : 0;
            fg += f;

            if (valid) {
                const float x = (b == 0) ? pc.x
                              : (b == 1) ? pc.y
                              : pred_cls[(size_t)b * A + a];
                const float p = 1.f / (1.f + expf(-x));
                const float l1p = log1pf(expf(-fabsf(x)));
                const float log_p  = fminf(x, 0.f) - l1p;    // log_sigmoid(x)
                const float log_np = fminf(-x, 0.f) - l1p;   // log_sigmoid(-x)
                const float pos = (label == 1.f) ? 1.f : 0.f;
                const float omp = 1.f - p;
                lc += -(F_ALPHA * pos * (omp * omp) * log_p
                        + (1.f - F_ALPHA) * (1.f - pos) * (p * p) * log_np);
            }

            if (f) {
                const float4 gb = eLo[lb + argp];      // originals
                const float gw = gb.z - gb.x + 1.f;
                const float gh = gb.w - gb.y + 1.f;
                const float gx = gb.x + 0.5f * gw;
                const float gy = gb.y + 0.5f * gh;
                const float axc = a0 + 0.5f * aw;
                const float ayc = a1 + 0.5f * ah;
                const float t0 = (gx - axc) / aw;
                const float t1 = (gy - ayc) / ah;
                const float t2 = logf(gw / aw);
                const float t3 = logf(gh / ah);
                const float4 rr = *reinterpret_cast<const float4*>(
                    pred_reg + 4 * ((size_t)b * A + a));   // rare fg gather
                lr += smooth_l1(rr.x - t0) + smooth_l1(rr.y - t1)
                    + smooth_l1(rr.z - t2) + smooth_l1(rr.w - t3);
            }
        }
    }

    // wave64 reduction + one relaxed-atomic triple per block.
    for (int off = 32; off > 0; off >>= 1) {
        lc += __shfl_down(lc, off);
        lr += __shfl_down(lr, off);
        fg += __shfl_down(fg, off);
    }
    __shared__ float s_lc[4], s_lr[4];
    __shared__ int s_np[4];
    const int wid = t >> 6;
    const int lane = t & 63;
    if (lane == 0) { s_lc[wid] = lc; s_lr[wid] = lr; s_np[wid] = fg; }
    __syncthreads();
    if (t == 0) {
        const float tlc = s_lc[0] + s_lc[1] + s_lc[2] + s_lc[3];
        const float tlr = s_lr[0] + s_lr[1] + s_lr[2] + s_lr[3];
        const int   tnp = s_np[0] + s_np[1] + s_np[2] + s_np[3];
        __hip_atomic_fetch_add(&ws[0],  (double)tlc, __ATOMIC_RELAXED, __HIP_MEMORY_SCOPE_AGENT);
        __hip_atomic_fetch_add(&ws[16], (double)tlr, __ATOMIC_RELAXED, __HIP_MEMORY_SCOPE_AGENT);
        __hip_atomic_fetch_add(&ws[32], (double)tnp, __ATOMIC_RELAXED, __HIP_MEMORY_SCOPE_AGENT);

        // Fused finalize: last block to arrive computes the output
        // (R14/R15-validated pattern, absmax 0.0).
        __threadfence();
        int* done = (int*)(ws + 48);           // byte 384, zeroed by k1
        const int prev = __hip_atomic_fetch_add(done, 1, __ATOMIC_ACQ_REL,
                                                __HIP_MEMORY_SCOPE_AGENT);
        if (prev == (int)gridDim.x - 1) {
            __threadfence();
            const double cls_s = __hip_atomic_load(&ws[0],  __ATOMIC_ACQUIRE, __HIP_MEMORY_SCOPE_AGENT);
            const double reg_s = __hip_atomic_load(&ws[16], __ATOMIC_ACQUIRE, __HIP_MEMORY_SCOPE_AGENT);
            const double np_s  = __hip_atomic_load(&ws[32], __ATOMIC_ACQUIRE, __HIP_MEMORY_SCOPE_AGENT);
            const double npos = np_s < 1.0 ? 1.0 : np_s;
            const double norm = 0.9 * 100.0 + 0.1 * npos;
            out[0] = (float)(cls_s / norm);
            out[1] = (float)(reg_s / norm);
        }
    }
}

extern "C" void kernel_launch(void* const* d_in, const int* in_sizes, int n_in,
                              void* d_out, int out_size, void* d_ws, size_t ws_size,
                              hipStream_t stream) {
    const float* pred_cls = (const float*)d_in[0];
    const float* pred_reg = (const float*)d_in[1];
    const float* anchors  = (const float*)d_in[2];
    const float* gt_boxes = (const float*)d_in[3];
    const float* im_info  = (const float*)d_in[4];

    const int A = in_sizes[2] / 4;
    const int B = in_sizes[4] / 6;
    const int G = in_sizes[3] / (B * 5);
    const int Gp = (G + 7) & ~7;
    const int nblk = (A + 256 * APT - 1) / (256 * APT);   // <= 256 required
    const int K1B = (nblk > NB) ? nblk : NB;              // hist + lists grid

    // ---- ws layout ----
    char* base = (char*)d_ws;
    double* ws = (double*)base;                  // [0,512): accum + done ctr
    size_t off = 512;
    float4* qLo = (float4*)(base + off);     off += (size_t)B * NB * Gp * 16;
    float* qA = (float*)(base + off);        off += (size_t)B * NB * Gp * 4;
    off = (off + 255) & ~(size_t)255;
    float4* eLo = (float4*)(base + off);     off += (size_t)B * NB * Gp * 16;
    float* eCls = (float*)(base + off);      off += (size_t)B * NB * Gp * 4;
    off = (off + 255) & ~(size_t)255;
    int* cnt_arr = (int*)(base + off);       off += (size_t)B * NB * 4;
    int* bucketid = (int*)(base + off);      off += (size_t)A * 4;
    int* sortedA = (int*)(base + off);       off += (size_t)A * 4;
    int* sortedbkt = (int*)(base + off);     off += (size_t)A * 4;
    off = (off + 255) & ~(size_t)255;
    float4* sortedAnc = (float4*)(base + off);  off += (size_t)A * 16;
    float4* sortedMeta = (float4*)(base + off); off += (size_t)A * 16;
    float2* sortedPc = (float2*)(base + off);   off += (size_t)A * 8;
    off = (off + 255) & ~(size_t)255;
    int* blockhist = (int*)(base + off);     off += (size_t)nblk * NB * 4;
    int* totals = (int*)(base + off);        off += (size_t)NB * 4;

    k1_assign_lists<<<K1B, 256, 0, stream>>>(
        anchors, gt_boxes, im_info, bucketid, blockhist,
        cnt_arr, qLo, qA, eLo, eCls, ws, A, G, Gp, B, nblk);
    k2_scan<<<NB, 256, 0, stream>>>(blockhist, totals, nblk);
    k3_place<<<nblk, 256, 0, stream>>>(anchors, pred_cls, bucketid, blockhist,
                                       totals, sortedA, sortedbkt, sortedAnc,
                                       sortedMeta, sortedPc, A, B);
    const int CH = (A + 255) / 256;
    retina_loss_kernel<<<CH, 256, 0, stream>>>(
        pred_reg, sortedA, sortedbkt, sortedAnc, sortedMeta, sortedPc,
        pred_cls, cnt_arr, qLo, qA, eLo, eCls, A, Gp, B, ws, (float*)d_out);
}

// Round 20
// 55.358 us; speedup vs baseline: 1.3869x; 1.3869x over previous
//
#include <hip/hip_runtime.h>
#include <math.h>

// CrowdDet RetinaNet loss constants
#define POS_T 0.5f
#define NEG_T 0.4f
#define F_ALPHA 0.25f
#define SL1_BETA 0.1f

// Pruning geometry (validated R10-R19): 8x8 cells of 128px, 6 area classes.
#define NCELL 8
#define NCLASS 6
#define NB (NCELL * NCELL * NCLASS)   // 384 buckets
#define KEEP_T 0.37f
#define APT 4                          // anchors per thread in k1/k3

// Anchor legacy-area class thresholds: 289 * 2.5^k (exact in f32).
__device__ __constant__ float AT[7] = {
    289.f, 722.5f, 1806.25f, 4515.625f, 11289.0625f, 28222.65625f, 70556.640625f};

__device__ __forceinline__ float smooth_l1(float d) {
    d = fabsf(d);
    return d < SL1_BETA ? 0.5f * d * d / SL1_BETA : d - SL1_BETA;
}

__device__ __forceinline__ int bucket_of(const float4 av) {
    const float aw = av.z - av.x + 1.f, ah = av.w - av.y + 1.f;
    const float Aa = aw * ah;
    const float cx = 0.5f * (av.x + av.z);
    const float cy = 0.5f * (av.y + av.w);
    const int cxi = min(NCELL - 1, max(0, (int)(cx * (1.0f / 128.f))));
    const int cyi = min(NCELL - 1, max(0, (int)(cy * (1.0f / 128.f))));
    const int k = (Aa > AT[1]) + (Aa > AT[2]) + (Aa > AT[3])
                + (Aa > AT[4]) + (Aa > AT[5]);
    return (k << 6) | (cyi << 3) | cxi;
}

// ---- K1: ws zero + anchor buckets/hist (blocks < nblk) + candidate lists
//          for bucket bk = blockIdx.x (all NB blocks). R19-validated
//          (absmax 0.0); removes list-building's serialization behind hist. --
__global__ __launch_bounds__(256) void k1_assign_lists(
    const float* __restrict__ anchors, const float* __restrict__ gt,
    const float* __restrict__ im_info,
    int* __restrict__ bucketid, int* __restrict__ blockhist, // [nblk][NB]
    int* __restrict__ cnt_arr,
    float4* __restrict__ qLo, float* __restrict__ qA,
    float4* __restrict__ eLo, float* __restrict__ eCls,
    double* __restrict__ ws, int A, int G, int Gp, int B, int nblk)
{
#pragma clang fp contract(off)
    __shared__ int lh[NB];
    const int t = threadIdx.x;
    const int blk = blockIdx.x;
    const int gid = blk * 256 + t;
    if (gid < 34) ws[gid] = 0.0;                 // loss accumulators

    // --- Part 1: hist + buckets (blocks < nblk) ---
    if (blk < nblk) {
        for (int i = t; i < NB; i += 256) lh[i] = 0;
        __syncthreads();
        #pragma unroll
        for (int u = 0; u < APT; ++u) {
            const int ai = blk * (256 * APT) + u * 256 + t;  // unit-stride
            if (ai < A) {
                const float4 av = *reinterpret_cast<const float4*>(anchors + 4 * (size_t)ai);
                const int bk = bucket_of(av);
                bucketid[ai] = bk;
                atomicAdd(&lh[bk], 1);           // LDS atomic, cheap
            }
        }
        __syncthreads();
        for (int j = t; j < NB; j += 256)
            blockhist[(size_t)blk * NB + j] = lh[j];   // coalesced burst
    }

    // --- Part 2: candidate lists for bucket bk = blk (validated keep-test;
    //     compaction preserves ascending gt order -> first-max intact) ---
    const int bk = blk;
    const int wid = t >> 6, lane = t & 63;
    const int cxi = bk & 7, cyi = (bk >> 3) & 7, k = bk >> 6;
    const float cx0 = cxi * 128.f, cx1 = cx0 + 128.f;
    const float cy0 = cyi * 128.f, cy1 = cy0 + 128.f;
    const float Alo = AT[k], Ahi = AT[k + 1];

    for (int b = wid; b < B; b += 4) {
        const int nv = __builtin_amdgcn_readfirstlane((int)im_info[b * 6 + 5]);
        const int li = b * NB + bk;
        const size_t lb = (size_t)li * Gp;

        int cnt = 0;
        for (int base = 0; base < nv; base += 64) {
            const int j = base + lane;
            bool keep = false;
            float g0 = 0.f, g1 = 0.f, g2 = 0.f, g3 = 0.f, cls = 0.f;
            float area = 0.f, g2p = 0.f, g3p = 0.f;
            if (j < nv) {
                const float* sp = gt + ((size_t)b * G + j) * 5;
                g0 = sp[0]; g1 = sp[1]; g2 = sp[2]; g3 = sp[3]; cls = sp[4];
                area = (g2 - g0 + 1.f) * (g3 - g1 + 1.f);   // exact ref order
                g2p = g2 + 1.f; g3p = g3 + 1.f;             // pre-added +1
                const float wg = g2p - g0;
                const float hg = g3p - g1;
                const float ox = fminf(cx1 + 129.f, g2p) - fmaxf(cx0 - 128.f, g0);
                const float oy = fminf(cy1 + 129.f, g3p) - fmaxf(cy0 - 128.f, g1);
                keep = (ox >= KEEP_T * wg) && (oy >= KEEP_T * hg)
                    && (area >= KEEP_T * Alo) && (KEEP_T * area <= Ahi);
            }
            const unsigned long long m = __ballot(keep);
            if (keep) {
                const int pos = cnt + __popcll(m & ((1ull << lane) - 1ull));
                qLo[lb + pos] = make_float4(g0, g1, g2p, g3p);
                qA[lb + pos] = area;
                eLo[lb + pos] = make_float4(g0, g1, g2, g3);
                eCls[lb + pos] = cls;
            }
            cnt += __popcll(m);
        }
        if (lane == 0) cnt_arr[li] = cnt;
    }
}

// ---- K2: scan-only — exclusive prefix of bh[blk][bk] over blk + totals ----
__global__ __launch_bounds__(256) void k2_scan(
    int* __restrict__ bh, int* __restrict__ totals, int nblk)
{
    const int bk = blockIdx.x, t = threadIdx.x;
    __shared__ int s[256];
    const int v = (t < nblk) ? bh[(size_t)t * NB + bk] : 0;
    s[t] = v;
    __syncthreads();
    for (int d = 1; d < 256; d <<= 1) {
        const int u = (t >= d) ? s[t - d] : 0;
        __syncthreads();
        s[t] += u;
        __syncthreads();
    }
    if (t < nblk) bh[(size_t)t * NB + bk] = s[t] - v;   // exclusive prefix
    if (t == 255) totals[bk] = s[255];
}

// ---- K3: bases + place anchors + PRE-GATHER per-anchor data to slot order --
// Verbatim R18 (absmax 0.0).
__global__ __launch_bounds__(256) void k3_place(
    const float* __restrict__ anchors, const float* __restrict__ pred_cls,
    const int* __restrict__ bucketid, const int* __restrict__ bh,
    const int* __restrict__ totals,
    int* __restrict__ sortedA, int* __restrict__ sortedbkt,
    float4* __restrict__ sortedAnc, float4* __restrict__ sortedMeta,
    float2* __restrict__ sortedPc, int A, int B)
{
#pragma clang fp contract(off)
    __shared__ int lh[NB];
    __shared__ int sbase[NB];
    const int t = threadIdx.x, blk = blockIdx.x;
    for (int i = t; i < NB; i += 256) lh[i] = 0;
    if (t < 64) {
        int carry = 0;
        #pragma unroll
        for (int r = 0; r < NB / 64; ++r) {
            int v = totals[r * 64 + t];            // exact (unpadded) bases
            const int orig = v;
            for (int d = 1; d < 64; d <<= 1) {
                const int u = __shfl_up(v, d);
                if (t >= d) v += u;
            }
            sbase[r * 64 + t] = carry + v - orig;  // exclusive
            carry += __shfl(v, 63);
        }
    }
    __syncthreads();

    #pragma unroll
    for (int u = 0; u < APT; ++u) {
        const int ai = blk * (256 * APT) + u * 256 + t;   // unit-stride reads
        if (ai < A) {
            const int bk = bucketid[ai];
            const int lrk = atomicAdd(&lh[bk], 1);
            const int slot = sbase[bk] + bh[(size_t)blk * NB + bk] + lrk;
            const float4 av = *reinterpret_cast<const float4*>(anchors + 4 * (size_t)ai);
            const float aw = av.z - av.x + 1.f;            // exact ref ops
            const float ah = av.w - av.y + 1.f;
            sortedA[slot] = ai;
            sortedbkt[slot] = bk;
            sortedAnc[slot] = make_float4(av.x, av.y, av.z + 1.f, av.w + 1.f);
            sortedMeta[slot] = make_float4(aw * ah, aw, ah, 0.f);
            const float pc0 = pred_cls[ai];
            const float pc1 = (B > 1) ? pred_cls[(size_t)A + ai] : 0.f;
            sortedPc[slot] = make_float2(pc0, pc1);
        }
    }
}

// ---- K5: main loss — verbatim R18 (absmax 0.0): slot-order coalesced reads,
//          indirection-free list walk, both batches per thread, NO fence. ---
__global__ __launch_bounds__(256) void retina_loss_kernel(
    const float* __restrict__ pred_reg,
    const int* __restrict__ sortedA, const int* __restrict__ sortedbkt,
    const float4* __restrict__ sortedAnc, const float4* __restrict__ sortedMeta,
    const float2* __restrict__ sortedPc, const float* __restrict__ pred_cls,
    const int* __restrict__ cnt_arr,
    const float4* __restrict__ qLo, const float* __restrict__ qA,
    const float4* __restrict__ eLo, const float* __restrict__ eCls,
    int A, int Gp, int B,
    double* __restrict__ ws)
{
#pragma clang fp contract(off)
    const int t = threadIdx.x;
    const int i_raw = blockIdx.x * 256 + t;
    const bool live = i_raw < A;
    const int i = min(i_raw, A - 1);

    const int a = sortedA[i];                 // coalesced
    const int bk = sortedbkt[i];              // near-uniform per wave
    const float4 anc = sortedAnc[i];          // {a0, a1, a2p, a3p}
    const float4 meta = sortedMeta[i];        // {area_a, aw, ah, -}
    const float2 pc = sortedPc[i];
    const float a0 = anc.x, a1 = anc.y, a2p = anc.z, a3p = anc.w;
    const float area_a = meta.x, aw = meta.y, ah = meta.z;

    float lc = 0.f, lr = 0.f;
    int fg = 0;

    for (int b = 0; b < B; ++b) {
        const int li = b * NB + bk;
        const int cnt = cnt_arr[li];
        const size_t lb = (size_t)li * Gp;

        // Division-free IoU argmax (validated): iou monotone in inter/S =>
        // strict cross-mul > == first-max (jnp.argmax tie-break). Induction-
        // only addresses -> loads pipeline ahead.
        float bi = -1.f, bS = 1.f;
        int argp = 0;
        for (int g = 0; g < cnt; ++g) {
            const float4 q = qLo[lb + g];     // broadcast (uniform-ish bk)
            const float sg = qA[lb + g];
            const float iw = fminf(a2p, q.z) - fmaxf(a0, q.x);
            const float ih = fminf(a3p, q.w) - fmaxf(a1, q.y);
            const float inter = fmaxf(iw, 0.f) * fmaxf(ih, 0.f);
            const float S = area_a + sg;
            const bool upd = inter * bS > bi * S;
            bi   = upd ? inter : bi;
            bS   = upd ? S     : bS;
            argp = upd ? g     : argp;
        }

        if (live) {
            // ONE division, exact ref expr: inter/((area_a+area_g)-inter).
            // cnt==0 -> max_ov=-0.5 -> bg (validated: pruned ious < 0.37).
            const float max_ov = bi / (bS - bi);

            float label = 0.f;
            bool valid = true;
            if (max_ov >= POS_T) {
                label = eCls[lb + argp];
            } else if (max_ov >= NEG_T) {
                valid = false;                 // ignore band
            }
            const int f = (label > 0.f) ? 1 : 0;
            fg += f;

            if (valid) {
                const float x = (b == 0) ? pc.x
                              : (b == 1) ? pc.y
                              : pred_cls[(size_t)b * A + a];
                const float p = 1.f / (1.f + expf(-x));
                const float l1p = log1pf(expf(-fabsf(x)));
                const float log_p  = fminf(x, 0.f) - l1p;    // log_sigmoid(x)
                const float log_np = fminf(-x, 0.f) - l1p;   // log_sigmoid(-x)
                const float pos = (label == 1.f) ? 1.f : 0.f;
                const float omp = 1.f - p;
                lc += -(F_ALPHA * pos * (omp * omp) * log_p
                        + (1.f - F_ALPHA) * (1.f - pos) * (p * p) * log_np);
            }

            if (f) {
                const float4 gb = eLo[lb + argp];      // originals
                const float gw = gb.z - gb.x + 1.f;
                const float gh = gb.w - gb.y + 1.f;
                const float gx = gb.x + 0.5f * gw;
                const float gy = gb.y + 0.5f * gh;
                const float axc = a0 + 0.5f * aw;
                const float ayc = a1 + 0.5f * ah;
                const float t0 = (gx - axc) / aw;
                const float t1 = (gy - ayc) / ah;
                const float t2 = logf(gw / aw);
                const float t3 = logf(gh / ah);
                const float4 rr = *reinterpret_cast<const float4*>(
                    pred_reg + 4 * ((size_t)b * A + a));   // rare fg gather
                lr += smooth_l1(rr.x - t0) + smooth_l1(rr.y - t1)
                    + smooth_l1(rr.z - t2) + smooth_l1(rr.w - t3);
            }
        }
    }

    // wave64 reduction + one relaxed-atomic triple per block (NO fence).
    for (int off = 32; off > 0; off >>= 1) {
        lc += __shfl_down(lc, off);
        lr += __shfl_down(lr, off);
        fg += __shfl_down(fg, off);
    }
    __shared__ float s_lc[4], s_lr[4];
    __shared__ int s_np[4];
    const int wid = t >> 6;
    const int lane = t & 63;
    if (lane == 0) { s_lc[wid] = lc; s_lr[wid] = lr; s_np[wid] = fg; }
    __syncthreads();
    if (t == 0) {
        const float tlc = s_lc[0] + s_lc[1] + s_lc[2] + s_lc[3];
        const float tlr = s_lr[0] + s_lr[1] + s_lr[2] + s_lr[3];
        const int   tnp = s_np[0] + s_np[1] + s_np[2] + s_np[3];
        __hip_atomic_fetch_add(&ws[0],  (double)tlc, __ATOMIC_RELAXED, __HIP_MEMORY_SCOPE_AGENT);
        __hip_atomic_fetch_add(&ws[16], (double)tlr, __ATOMIC_RELAXED, __HIP_MEMORY_SCOPE_AGENT);
        __hip_atomic_fetch_add(&ws[32], (double)tnp, __ATOMIC_RELAXED, __HIP_MEMORY_SCOPE_AGENT);
    }
}

__global__ void finalize_kernel(const double* __restrict__ ws, float* __restrict__ out) {
    if (threadIdx.x == 0 && blockIdx.x == 0) {
        const double npos = ws[32] < 1.0 ? 1.0 : ws[32];
        const double norm = 0.9 * 100.0 + 0.1 * npos;
        out[0] = (float)(ws[0] / norm);
        out[1] = (float)(ws[16] / norm);
    }
}

extern "C" void kernel_launch(void* const* d_in, const int* in_sizes, int n_in,
                              void* d_out, int out_size, void* d_ws, size_t ws_size,
                              hipStream_t stream) {
    const float* pred_cls = (const float*)d_in[0];
    const float* pred_reg = (const float*)d_in[1];
    const float* anchors  = (const float*)d_in[2];
    const float* gt_boxes = (const float*)d_in[3];
    const float* im_info  = (const float*)d_in[4];

    const int A = in_sizes[2] / 4;
    const int B = in_sizes[4] / 6;
    const int G = in_sizes[3] / (B * 5);
    const int Gp = (G + 7) & ~7;
    const int nblk = (A + 256 * APT - 1) / (256 * APT);   // <= 256 required
    const int K1B = (nblk > NB) ? nblk : NB;              // hist + lists grid

    // ---- ws layout ----
    char* base = (char*)d_ws;
    double* ws = (double*)base;                  // [0,512): accumulators
    size_t off = 512;
    float4* qLo = (float4*)(base + off);     off += (size_t)B * NB * Gp * 16;
    float* qA = (float*)(base + off);        off += (size_t)B * NB * Gp * 4;
    off = (off + 255) & ~(size_t)255;
    float4* eLo = (float4*)(base + off);     off += (size_t)B * NB * Gp * 16;
    float* eCls = (float*)(base + off);      off += (size_t)B * NB * Gp * 4;
    off = (off + 255) & ~(size_t)255;
    int* cnt_arr = (int*)(base + off);       off += (size_t)B * NB * 4;
    int* bucketid = (int*)(base + off);      off += (size_t)A * 4;
    int* sortedA = (int*)(base + off);       off += (size_t)A * 4;
    int* sortedbkt = (int*)(base + off);     off += (size_t)A * 4;
    off = (off + 255) & ~(size_t)255;
    float4* sortedAnc = (float4*)(base + off);  off += (size_t)A * 16;
    float4* sortedMeta = (float4*)(base + off); off += (size_t)A * 16;
    float2* sortedPc = (float2*)(base + off);   off += (size_t)A * 8;
    off = (off + 255) & ~(size_t)255;
    int* blockhist = (int*)(base + off);     off += (size_t)nblk * NB * 4;
    int* totals = (int*)(base + off);        off += (size_t)NB * 4;

    k1_assign_lists<<<K1B, 256, 0, stream>>>(
        anchors, gt_boxes, im_info, bucketid, blockhist,
        cnt_arr, qLo, qA, eLo, eCls, ws, A, G, Gp, B, nblk);
    k2_scan<<<NB, 256, 0, stream>>>(blockhist, totals, nblk);
    k3_place<<<nblk, 256, 0, stream>>>(anchors, pred_cls, bucketid, blockhist,
                                       totals, sortedA, sortedbkt, sortedAnc,
                                       sortedMeta, sortedPc, A, B);
    const int CH = (A + 255) / 256;
    retina_loss_kernel<<<CH, 256, 0, stream>>>(
        pred_reg, sortedA, sortedbkt, sortedAnc, sortedMeta, sortedPc,
        pred_cls, cnt_arr, qLo, qA, eLo, eCls, A, Gp, B, ws);
    finalize_kernel<<<1, 1, 0, stream>>>(ws, (float*)d_out);
}